// Round 2
// baseline (834.554 us; speedup 1.0000x reference)
//
#include <hip/hip_runtime.h>
#include <math.h>

// N=B*H*W=8192 tokens, K=8192 codes, D=256 dims.
// Key numerics: harness reference is numpy fp32. Argmax of softmax == first-
// occurrence argmax of x = fl(g - fl(A_n - M_nk)) where A_n = np-pairwise
// fp32 sum of fl(f^2) (B_k = ||w||^2 ~1.3e-6 < ulp(A)/2 always rounds away),
// M = (2f)@W^T via fp32 FMA chain (association slack absorbed by ulp(256)
// quantization). A_n must be BIT-EXACT numpy pairwise; use __f*_rn to defeat
// -ffp-contract=fast.

// ---------------- transpose z_e (NCHW) -> flat2 = 2*z_e as [N, D] ----------------
__global__ void vq_transpose(const float* __restrict__ z_e, float* __restrict__ flat2) {
  __shared__ float tile[256][33];
  const int bx = blockIdx.x;  // b*32 + h
  const int b = bx >> 5, h = bx & 31;
  const int tid = threadIdx.x;
  const int w = tid & 31, dg = tid >> 5;
  const size_t zbase = (size_t)b * (256 * 1024) + (size_t)h * 32;
#pragma unroll 4
  for (int it = 0; it < 32; ++it) {
    const int d = dg * 32 + it;
    tile[d][w] = 2.0f * z_e[zbase + (size_t)d * 1024 + w];  // exact doubling
  }
  __syncthreads();
  const int n0 = bx * 32;
#pragma unroll 4
  for (int w2 = 0; w2 < 32; ++w2) {
    flat2[(size_t)(n0 + w2) * 256 + tid] = tile[tid][w2];
  }
}

// ---------------- A_n = numpy-pairwise fp32 sum of fl(f^2), from q=2f ----------------
// numpy: n=256 -> pw(0:128)+pw(128:256); each 128-block: 8 accumulators,
// combine ((r0+r1)+(r2+r3))+((r4+r5)+(r6+r7)). fl(f^2) = fl(q*q)*0.25f.
__device__ __forceinline__ float sq025(float q) {
  return __fmul_rn(__fmul_rn(q, q), 0.25f);
}
__global__ void vq_rowsumA(const float* __restrict__ flat2, float* __restrict__ A) {
  const int n = blockIdx.x * 256 + threadIdx.x;
  const float4* p4 = (const float4*)(flat2 + (size_t)n * 256);
  float hsum[2];
#pragma unroll
  for (int half = 0; half < 2; ++half) {
    const float4* p = p4 + half * 32;
    float4 v0 = p[0], v1 = p[1];
    float r0 = sq025(v0.x), r1 = sq025(v0.y), r2 = sq025(v0.z), r3 = sq025(v0.w);
    float r4 = sq025(v1.x), r5 = sq025(v1.y), r6 = sq025(v1.z), r7 = sq025(v1.w);
#pragma unroll
    for (int i = 2; i < 32; i += 2) {
      v0 = p[i]; v1 = p[i + 1];
      r0 = __fadd_rn(r0, sq025(v0.x)); r1 = __fadd_rn(r1, sq025(v0.y));
      r2 = __fadd_rn(r2, sq025(v0.z)); r3 = __fadd_rn(r3, sq025(v0.w));
      r4 = __fadd_rn(r4, sq025(v1.x)); r5 = __fadd_rn(r5, sq025(v1.y));
      r6 = __fadd_rn(r6, sq025(v1.z)); r7 = __fadd_rn(r7, sq025(v1.w));
    }
    hsum[half] = __fadd_rn(__fadd_rn(__fadd_rn(r0, r1), __fadd_rn(r2, r3)),
                           __fadd_rn(__fadd_rn(r4, r5), __fadd_rn(r6, r7)));
  }
  A[n] = __fadd_rn(hsum[0], hsum[1]);
}

// ---------------- fused GEMM (M = (2f)@W^T) + fp32 score + per-slice argmax ----------------
__global__ __launch_bounds__(256, 2) void vq_score_argmax(
    const float* __restrict__ flat2, const float* __restrict__ weight,
    const float* __restrict__ gumbel, const float* __restrict__ Arow,
    float2* __restrict__ cand) {
  __shared__ float As[128][36];  // holds q=2f; stride 36 -> <=2-way conflicts
  __shared__ float Ws[128][36];
  __shared__ float2 red[128][16];

  const int tid = threadIdx.x;
  const int tx = tid & 15, ty = tid >> 4;
  const int n0 = blockIdx.x * 128;
  const int kb = blockIdx.y * 1024;

  float Ai[8];
#pragma unroll
  for (int i = 0; i < 8; ++i) Ai[i] = Arow[n0 + ty + 16 * i];

  float best_v[8];
  int best_k[8];
#pragma unroll
  for (int i = 0; i < 8; ++i) { best_v[i] = -1e30f; best_k[i] = 0; }

#pragma unroll 1
  for (int kc = 0; kc < 8; ++kc) {
    const int k0 = kb + kc * 128;
    float acc[8][8];
#pragma unroll
    for (int i = 0; i < 8; ++i)
#pragma unroll
      for (int j = 0; j < 8; ++j) acc[i][j] = 0.f;

#pragma unroll 1
    for (int dc = 0; dc < 8; ++dc) {  // ascending d: matches BLAS k-order chain
      const int d0 = dc * 32;
      __syncthreads();
#pragma unroll
      for (int p = 0; p < 4; ++p) {
        const int pos = tid + 256 * p;
        const int row = pos >> 3, c4 = (pos & 7) * 4;
        const float4 av = *(const float4*)(flat2 + (size_t)(n0 + row) * 256 + d0 + c4);
        *(float4*)(&As[row][c4]) = av;
        const float4 wv = *(const float4*)(weight + (size_t)(k0 + row) * 256 + d0 + c4);
        *(float4*)(&Ws[row][c4]) = wv;
      }
      __syncthreads();
#pragma unroll
      for (int dd = 0; dd < 32; dd += 4) {
        float4 a4[8], b4[8];
#pragma unroll
        for (int i = 0; i < 8; ++i) a4[i] = *(const float4*)(&As[ty + 16 * i][dd]);
#pragma unroll
        for (int j = 0; j < 8; ++j) b4[j] = *(const float4*)(&Ws[tx + 16 * j][dd]);
#pragma unroll
        for (int i = 0; i < 8; ++i)
#pragma unroll
          for (int j = 0; j < 8; ++j) {
            // single fp32 FMA chain, ascending d — mimics sgemm accumulation
            acc[i][j] = __fmaf_rn(a4[i].x, b4[j].x, acc[i][j]);
            acc[i][j] = __fmaf_rn(a4[i].y, b4[j].y, acc[i][j]);
            acc[i][j] = __fmaf_rn(a4[i].z, b4[j].z, acc[i][j]);
            acc[i][j] = __fmaf_rn(a4[i].w, b4[j].w, acc[i][j]);
          }
      }
    }
    // epilogue: x = fl(g - fl(A - M)); first-occurrence argmax (k ascending)
#pragma unroll
    for (int i = 0; i < 8; ++i) {
      const float* grow = gumbel + (size_t)(n0 + ty + 16 * i) * 8192 + k0;
#pragma unroll
      for (int j = 0; j < 8; ++j) {
        const float t2 = __fsub_rn(Ai[i], acc[i][j]);
        const float s = __fsub_rn(grow[tx + 16 * j], t2);
        if (s > best_v[i]) { best_v[i] = s; best_k[i] = k0 + tx + 16 * j; }
      }
    }
  }

  __syncthreads();
#pragma unroll
  for (int i = 0; i < 8; ++i)
    red[ty + 16 * i][tx] = make_float2(best_v[i], (float)best_k[i]);
  __syncthreads();
  if (tid < 128) {
    float2 bb = red[tid][0];
#pragma unroll
    for (int t = 1; t < 16; ++t) {
      const float2 c = red[tid][t];
      if (c.x > bb.x || (c.x == bb.x && c.y < bb.y)) bb = c;  // tie -> smaller k
    }
    cand[(size_t)(n0 + tid) * 8 + blockIdx.y] = bb;
  }
}

// ---------------- reduce 8 slice-candidates per token ----------------
__global__ void vq_reduce_cand(const float2* __restrict__ cand, int* __restrict__ idxbuf,
                               int* __restrict__ hist, float* __restrict__ out_idx) {
  const int n = blockIdx.x * 256 + threadIdx.x;
  float2 b = cand[(size_t)n * 8];
#pragma unroll
  for (int s = 1; s < 8; ++s) {  // ascending-k slices
    const float2 c = cand[(size_t)n * 8 + s];
    if (c.x > b.x || (c.x == b.x && c.y < b.y)) b = c;
  }
  const int k = (int)b.y;
  idxbuf[n] = k;
  out_idx[n] = b.y;  // fp32-exact for k < 2^24
  atomicAdd(&hist[k], 1);
}

// ---------------- gather z_q, STE output (NCHW), loss partials ----------------
__global__ void vq_gather_out(const float* __restrict__ z_e, const float* __restrict__ weight,
                              const int* __restrict__ idxbuf, float* __restrict__ out0,
                              float* __restrict__ lpart) {
  __shared__ int sidx[32];
  __shared__ float sred[256];
  const int bx = blockIdx.x;
  const int b = bx >> 5, h = bx & 31;
  const int tid = threadIdx.x;
  if (tid < 32) sidx[tid] = idxbuf[bx * 32 + tid];
  __syncthreads();
  const int w = tid & 31;
  const int dg = tid >> 5;
  const int srow = sidx[w];
  const size_t base = (size_t)b * (256 * 1024) + (size_t)h * 32 + w;
  float part = 0.f;
#pragma unroll 4
  for (int it = 0; it < 32; ++it) {
    const int d = dg * 32 + it;
    const float q = weight[(size_t)srow * 256 + d];
    const size_t a = base + (size_t)d * 1024;
    const float ze = z_e[a];
    const float df = q - ze;
    out0[a] = ze + df;  // fl(ze + fl(q - ze)) as in reference STE
    part = fmaf(df, df, part);
  }
  sred[tid] = part;
  __syncthreads();
#pragma unroll
  for (int off = 128; off > 0; off >>= 1) {
    if (tid < off) sred[tid] += sred[tid + off];
    __syncthreads();
  }
  if (tid == 0) lpart[bx] = sred[0];
}

// ---------------- scalars: vq_loss, perplexity ----------------
__global__ void vq_finalize(const float* __restrict__ lpart, const int* __restrict__ hist,
                            float* __restrict__ out) {
  __shared__ double sd[256];
  const int tid = threadIdx.x;
  sd[tid] = (double)lpart[tid];
  __syncthreads();
#pragma unroll
  for (int off = 128; off > 0; off >>= 1) {
    if (tid < off) sd[tid] += sd[tid + off];
    __syncthreads();
  }
  if (tid == 0) out[2097152] = (float)(1.25 * sd[0] / 2097152.0);
  __syncthreads();
  double hh = 0.0;
#pragma unroll 4
  for (int q = 0; q < 32; ++q) {
    const int c = hist[tid * 32 + q];
    const double p = (double)c / 8192.0;
    hh += p * log(p + 1e-10);
  }
  sd[tid] = hh;
  __syncthreads();
#pragma unroll
  for (int off = 128; off > 0; off >>= 1) {
    if (tid < off) sd[tid] += sd[tid + off];
    __syncthreads();
  }
  if (tid == 0) out[2097153] = (float)exp(-sd[0]);
}

extern "C" void kernel_launch(void* const* d_in, const int* in_sizes, int n_in,
                              void* d_out, int out_size, void* d_ws, size_t ws_size,
                              hipStream_t stream) {
  const float* z_e = (const float*)d_in[0];     // [8,256,32,32]
  const float* weight = (const float*)d_in[1];  // [8192,256]
  const float* gumbel = (const float*)d_in[2];  // [8192,8192]
  float* out = (float*)d_out;  // [z_q_ste 2097152][vq_loss][perplexity][indices 8192]

  float* ws = (float*)d_ws;
  float* Arow = ws;                                          // 8192
  float2* cand = (float2*)(ws + 8192);                       // 8192*8 float2 = 131072 floats
  int* hist = (int*)(ws + 8192 + 131072);                    // 8192
  float* lpart = ws + 8192 + 131072 + 8192;                  // 256
  int* idxbuf = (int*)(ws + 8192 + 131072 + 8192 + 256);     // 8192
  const size_t small_floats = 8192 + 131072 + 8192 + 256 + 8192;  // 155904
  // flat2 [8192][256]: in ws if it fits, else stage in out[0..2M) (consumed
  // before vq_gather_out overwrites that region).
  float* flat2 = (ws_size >= (small_floats + 2097152) * sizeof(float))
                     ? (ws + small_floats)
                     : out;

  hipMemsetAsync(hist, 0, 8192 * sizeof(int), stream);
  vq_transpose<<<256, 256, 0, stream>>>(z_e, flat2);
  vq_rowsumA<<<32, 256, 0, stream>>>(flat2, Arow);
  vq_score_argmax<<<dim3(64, 8), 256, 0, stream>>>(flat2, weight, gumbel, Arow, cand);
  vq_reduce_cand<<<32, 256, 0, stream>>>(cand, idxbuf, hist, out + 2097154);
  vq_gather_out<<<256, 256, 0, stream>>>(z_e, weight, idxbuf, out, lpart);
  vq_finalize<<<1, 256, 0, stream>>>(lpart, hist, out);
}

// Round 3
// 625.456 us; speedup vs baseline: 1.3343x; 1.3343x over previous
//
#include <hip/hip_runtime.h>
#include <math.h>

// N=B*H*W=8192 tokens, K=8192 codes, D=256 dims.
// Numerics (proven bit-exact in round 2): argmax over k of
//   s = fl(g - fl(A_n - M_nk)),  A_n = numpy-pairwise fp32 sum of fl(f^2)
//   (B_k=||w||^2 ~1.3e-6 < ulp(A)/2 always rounds away), M = (2f)@W^T with
//   ~1e-9 association slack vs host sgemm.
// Round 3: compute M via 6-pass split-bf16 MFMA (exact 3-term bf16 split of
// each fp32 operand; products hh,hm,mh,mm,hl,lh accumulated in one fp32
// accumulator). Residual vs fp32 chain ~3e-11 << 1e-9 slack.

typedef __attribute__((ext_vector_type(8))) short bf16x8;
typedef __attribute__((ext_vector_type(4))) float floatx4;

__device__ __forceinline__ float sq025(float q) {
  return __fmul_rn(__fmul_rn(q, q), 0.25f);
}
__device__ __forceinline__ unsigned short bf16_rne(float x) {
  unsigned int u = __float_as_uint(x);
  unsigned int r = (u + 0x7FFFu + ((u >> 16) & 1u)) >> 16;
  return (unsigned short)r;
}
__device__ __forceinline__ float bf16f(unsigned short h) {
  return __uint_as_float(((unsigned int)h) << 16);
}

// ---------------- transpose z_e (NCHW) -> flat2=2*z_e [N,D] + A_n (fused) ----------------
__global__ void vq_transpose_rowsum(const float* __restrict__ z_e,
                                    float* __restrict__ flat2,
                                    float* __restrict__ Arow) {
  __shared__ float tile[256][36];  // stride 36: 2-way max on both phases
  const int bx = blockIdx.x;       // b*32 + h
  const int b = bx >> 5, h = bx & 31;
  const int tid = threadIdx.x;
  const int w = tid & 31, dg = tid >> 5;
  const size_t zbase = (size_t)b * (256 * 1024) + (size_t)h * 32;
#pragma unroll 4
  for (int it = 0; it < 32; ++it) {
    const int d = dg * 32 + it;
    tile[d][w] = 2.0f * z_e[zbase + (size_t)d * 1024 + w];  // exact doubling
  }
  __syncthreads();
  const int n0 = bx * 32;
#pragma unroll 4
  for (int w2 = 0; w2 < 32; ++w2)
    flat2[(size_t)(n0 + w2) * 256 + tid] = tile[tid][w2];
  // numpy pairwise ||f||^2 from q=2f: 8 threads/token, r_j chains + exact tree.
  const int tg = tid >> 3, j = tid & 7;
  float halfs[2];
#pragma unroll
  for (int hh = 0; hh < 2; ++hh) {
    float r = sq025(tile[hh * 128 + j][tg]);
#pragma unroll
    for (int i = 1; i < 16; ++i)
      r = __fadd_rn(r, sq025(tile[hh * 128 + 8 * i + j][tg]));
    const float t2 = __fadd_rn(r, __shfl_xor(r, 1, 64));
    const float t4 = __fadd_rn(t2, __shfl_xor(t2, 2, 64));
    halfs[hh] = __fadd_rn(t4, __shfl_xor(t4, 4, 64));
  }
  if (j == 0) Arow[n0 + tg] = __fadd_rn(halfs[0], halfs[1]);
}

// ---------------- exact 3-term bf16 split of an fp32 matrix ----------------
__global__ void vq_split(const float* __restrict__ src, unsigned short* __restrict__ hi,
                         unsigned short* __restrict__ mid, unsigned short* __restrict__ lo) {
  const int u = blockIdx.x * 256 + threadIdx.x;  // float4 index, 524288 total
  const float4 v = ((const float4*)src)[u];
  float a[4] = {v.x, v.y, v.z, v.w};
  unsigned short rh[4], rm[4], rl[4];
#pragma unroll
  for (int i = 0; i < 4; ++i) {
    rh[i] = bf16_rne(a[i]);
    const float r1 = __fsub_rn(a[i], bf16f(rh[i]));
    rm[i] = bf16_rne(r1);
    const float r2 = __fsub_rn(r1, bf16f(rm[i]));
    rl[i] = bf16_rne(r2);  // hi+mid+lo == a exactly (<=24 mantissa bits)
  }
  ushort4 oh = {rh[0], rh[1], rh[2], rh[3]};
  ushort4 om = {rm[0], rm[1], rm[2], rm[3]};
  ushort4 ol = {rl[0], rl[1], rl[2], rl[3]};
  ((ushort4*)hi)[u] = oh;
  ((ushort4*)mid)[u] = om;
  ((ushort4*)lo)[u] = ol;
}

// ---------------- MFMA score + argmax: grid(64 n-tiles, 64 k-tiles) ----------------
#define LSTR 40  // shorts; 80B row stride: 16B-aligned, uniform 2-way banks
__global__ __launch_bounds__(256, 2) void vq_score_mfma(
    const unsigned short* __restrict__ ah, const unsigned short* __restrict__ am,
    const unsigned short* __restrict__ al, const unsigned short* __restrict__ wh,
    const unsigned short* __restrict__ wm, const unsigned short* __restrict__ wl,
    const float* __restrict__ gumbel, const float* __restrict__ Arow,
    float2* __restrict__ cand) {
  __shared__ unsigned short sA[3][128][LSTR];
  __shared__ unsigned short sW[3][128][LSTR];
  __shared__ float2 red[128][2];

  const int tid = threadIdx.x;
  const int wv = tid >> 6, lane = tid & 63;
  const int r16 = lane & 15, q = lane >> 4;
  const int wrow = (wv & 1) * 64, wcol = (wv >> 1) * 64;
  const int n0 = blockIdx.x * 128, k0 = blockIdx.y * 128;

  floatx4 acc[4][4];
#pragma unroll
  for (int i = 0; i < 4; ++i)
#pragma unroll
    for (int j = 0; j < 4; ++j) acc[i][j] = (floatx4){0.f, 0.f, 0.f, 0.f};

  const unsigned short* gA[3] = {ah, am, al};
  const unsigned short* gW[3] = {wh, wm, wl};

#pragma unroll 1
  for (int dc = 0; dc < 8; ++dc) {  // 8 chunks of 32 d == one MFMA-K each
    const int d0 = dc * 32;
    __syncthreads();
#pragma unroll
    for (int c = 0; c < 3; ++c)
#pragma unroll
      for (int p = 0; p < 2; ++p) {
        const int chunk = tid + 256 * p;          // 512 x 16B per matrix comp
        const int row = chunk >> 2, c8 = (chunk & 3) * 8;
        *(uint4*)&sA[c][row][c8] =
            *(const uint4*)(gA[c] + (size_t)(n0 + row) * 256 + d0 + c8);
        *(uint4*)&sW[c][row][c8] =
            *(const uint4*)(gW[c] + (size_t)(k0 + row) * 256 + d0 + c8);
      }
    __syncthreads();
    bf16x8 af[3][4], bf[3][4];
#pragma unroll
    for (int c = 0; c < 3; ++c)
#pragma unroll
      for (int i = 0; i < 4; ++i) {
        af[c][i] = *(const bf16x8*)&sA[c][wrow + i * 16 + r16][q * 8];
        bf[c][i] = *(const bf16x8*)&sW[c][wcol + i * 16 + r16][q * 8];
      }
#pragma unroll
    for (int i = 0; i < 4; ++i)
#pragma unroll
      for (int j = 0; j < 4; ++j) {
        floatx4 a = acc[i][j];
        a = __builtin_amdgcn_mfma_f32_16x16x32_bf16(af[0][i], bf[0][j], a, 0, 0, 0);
        a = __builtin_amdgcn_mfma_f32_16x16x32_bf16(af[0][i], bf[1][j], a, 0, 0, 0);
        a = __builtin_amdgcn_mfma_f32_16x16x32_bf16(af[1][i], bf[0][j], a, 0, 0, 0);
        a = __builtin_amdgcn_mfma_f32_16x16x32_bf16(af[1][i], bf[1][j], a, 0, 0, 0);
        a = __builtin_amdgcn_mfma_f32_16x16x32_bf16(af[0][i], bf[2][j], a, 0, 0, 0);
        a = __builtin_amdgcn_mfma_f32_16x16x32_bf16(af[2][i], bf[0][j], a, 0, 0, 0);
        acc[i][j] = a;
      }
  }
  // epilogue: s = fl(g - fl(A - M)); C/D map col=lane&15, row=q*4+reg (m89/m91)
#pragma unroll
  for (int i = 0; i < 4; ++i) {
#pragma unroll
    for (int rg = 0; rg < 4; ++rg) {
      const int nloc = wrow + i * 16 + q * 4 + rg;
      const float Av = Arow[n0 + nloc];
      const float* grow = gumbel + (size_t)(n0 + nloc) * 8192 + k0 + wcol + r16;
      float bv = -3.4e38f;
      int bk = 0x7fffffff;
#pragma unroll
      for (int j = 0; j < 4; ++j) {  // ascending k
        const float t2 = __fsub_rn(Av, acc[i][j][rg]);
        const float s = __fsub_rn(grow[j * 16], t2);
        const int kk = k0 + wcol + j * 16 + r16;
        if (s > bv) { bv = s; bk = kk; }
      }
#pragma unroll
      for (int m = 1; m < 16; m <<= 1) {  // quad-local: same token row
        const float ov = __shfl_xor(bv, m, 64);
        const int ok = __shfl_xor(bk, m, 64);
        if (ov > bv || (ov == bv && ok < bk)) { bv = ov; bk = ok; }
      }
      if (r16 == 0) red[nloc][wv >> 1] = make_float2(bv, (float)bk);
    }
  }
  __syncthreads();
  if (tid < 128) {
    float2 bb = red[tid][0];  // lower-k half first: first-occurrence ties
    const float2 c = red[tid][1];
    if (c.x > bb.x || (c.x == bb.x && c.y < bb.y)) bb = c;
    cand[(size_t)(n0 + tid) * 64 + blockIdx.y] = bb;
  }
}

// ---------------- fallback fp32 score kernel (round-2 proven) ----------------
__global__ __launch_bounds__(256, 2) void vq_score_argmax(
    const float* __restrict__ flat2, const float* __restrict__ weight,
    const float* __restrict__ gumbel, const float* __restrict__ Arow,
    float2* __restrict__ cand) {
  __shared__ float As[128][36];
  __shared__ float Ws[128][36];
  __shared__ float2 red[128][16];
  const int tid = threadIdx.x;
  const int tx = tid & 15, ty = tid >> 4;
  const int n0 = blockIdx.x * 128;
  const int kb = blockIdx.y * 1024;
  float Ai[8];
#pragma unroll
  for (int i = 0; i < 8; ++i) Ai[i] = Arow[n0 + ty + 16 * i];
  float best_v[8];
  int best_k[8];
#pragma unroll
  for (int i = 0; i < 8; ++i) { best_v[i] = -1e30f; best_k[i] = 0; }
#pragma unroll 1
  for (int kc = 0; kc < 8; ++kc) {
    const int k0 = kb + kc * 128;
    float acc[8][8];
#pragma unroll
    for (int i = 0; i < 8; ++i)
#pragma unroll
      for (int j = 0; j < 8; ++j) acc[i][j] = 0.f;
#pragma unroll 1
    for (int dc = 0; dc < 8; ++dc) {
      const int d0 = dc * 32;
      __syncthreads();
#pragma unroll
      for (int p = 0; p < 4; ++p) {
        const int pos = tid + 256 * p;
        const int row = pos >> 3, c4 = (pos & 7) * 4;
        *(float4*)(&As[row][c4]) =
            *(const float4*)(flat2 + (size_t)(n0 + row) * 256 + d0 + c4);
        *(float4*)(&Ws[row][c4]) =
            *(const float4*)(weight + (size_t)(k0 + row) * 256 + d0 + c4);
      }
      __syncthreads();
#pragma unroll
      for (int dd = 0; dd < 32; dd += 4) {
        float4 a4[8], b4[8];
#pragma unroll
        for (int i = 0; i < 8; ++i) a4[i] = *(const float4*)(&As[ty + 16 * i][dd]);
#pragma unroll
        for (int j = 0; j < 8; ++j) b4[j] = *(const float4*)(&Ws[tx + 16 * j][dd]);
#pragma unroll
        for (int i = 0; i < 8; ++i)
#pragma unroll
          for (int j = 0; j < 8; ++j) {
            acc[i][j] = __fmaf_rn(a4[i].x, b4[j].x, acc[i][j]);
            acc[i][j] = __fmaf_rn(a4[i].y, b4[j].y, acc[i][j]);
            acc[i][j] = __fmaf_rn(a4[i].z, b4[j].z, acc[i][j]);
            acc[i][j] = __fmaf_rn(a4[i].w, b4[j].w, acc[i][j]);
          }
      }
    }
#pragma unroll
    for (int i = 0; i < 8; ++i) {
      const float* grow = gumbel + (size_t)(n0 + ty + 16 * i) * 8192 + k0;
#pragma unroll
      for (int j = 0; j < 8; ++j) {
        const float t2 = __fsub_rn(Ai[i], acc[i][j]);
        const float s = __fsub_rn(grow[tx + 16 * j], t2);
        if (s > best_v[i]) { best_v[i] = s; best_k[i] = k0 + tx + 16 * j; }
      }
    }
  }
  __syncthreads();
#pragma unroll
  for (int i = 0; i < 8; ++i)
    red[ty + 16 * i][tx] = make_float2(best_v[i], (float)best_k[i]);
  __syncthreads();
  if (tid < 128) {
    float2 bb = red[tid][0];
#pragma unroll
    for (int t = 1; t < 16; ++t) {
      const float2 c = red[tid][t];
      if (c.x > bb.x || (c.x == bb.x && c.y < bb.y)) bb = c;
    }
    cand[(size_t)(n0 + tid) * 8 + blockIdx.y] = bb;
  }
}

// ---------------- reduce slice-candidates per token ----------------
__global__ void vq_reduce_cand(const float2* __restrict__ cand, const int nslice,
                               int* __restrict__ idxbuf, int* __restrict__ hist,
                               float* __restrict__ out_idx) {
  const int n = blockIdx.x * 256 + threadIdx.x;
  float2 b = cand[(size_t)n * nslice];
  for (int s = 1; s < nslice; ++s) {  // ascending-k slices
    const float2 c = cand[(size_t)n * nslice + s];
    if (c.x > b.x || (c.x == b.x && c.y < b.y)) b = c;
  }
  const int k = (int)b.y;
  idxbuf[n] = k;
  out_idx[n] = b.y;
  atomicAdd(&hist[k], 1);
}

// ---------------- gather z_q, STE output (NCHW), loss partials ----------------
__global__ void vq_gather_out(const float* __restrict__ z_e, const float* __restrict__ weight,
                              const int* __restrict__ idxbuf, float* __restrict__ out0,
                              float* __restrict__ lpart) {
  __shared__ int sidx[32];
  __shared__ float sred[256];
  const int bx = blockIdx.x;
  const int b = bx >> 5, h = bx & 31;
  const int tid = threadIdx.x;
  if (tid < 32) sidx[tid] = idxbuf[bx * 32 + tid];
  __syncthreads();
  const int w = tid & 31;
  const int dg = tid >> 5;
  const int srow = sidx[w];
  const size_t base = (size_t)b * (256 * 1024) + (size_t)h * 32 + w;
  float part = 0.f;
#pragma unroll 4
  for (int it = 0; it < 32; ++it) {
    const int d = dg * 32 + it;
    const float qv = weight[(size_t)srow * 256 + d];
    const size_t a = base + (size_t)d * 1024;
    const float ze = z_e[a];
    const float df = qv - ze;
    out0[a] = ze + df;
    part = fmaf(df, df, part);
  }
  sred[tid] = part;
  __syncthreads();
#pragma unroll
  for (int off = 128; off > 0; off >>= 1) {
    if (tid < off) sred[tid] += sred[tid + off];
    __syncthreads();
  }
  if (tid == 0) lpart[bx] = sred[0];
}

// ---------------- scalars: vq_loss, perplexity ----------------
__global__ void vq_finalize(const float* __restrict__ lpart, const int* __restrict__ hist,
                            float* __restrict__ out) {
  __shared__ double sd[256];
  const int tid = threadIdx.x;
  sd[tid] = (double)lpart[tid];
  __syncthreads();
#pragma unroll
  for (int off = 128; off > 0; off >>= 1) {
    if (tid < off) sd[tid] += sd[tid + off];
    __syncthreads();
  }
  if (tid == 0) out[2097152] = (float)(1.25 * sd[0] / 2097152.0);
  __syncthreads();
  double hh = 0.0;
#pragma unroll 4
  for (int qq = 0; qq < 32; ++qq) {
    const int c = hist[tid * 32 + qq];
    const double p = (double)c / 8192.0;
    hh += p * log(p + 1e-10);
  }
  sd[tid] = hh;
  __syncthreads();
#pragma unroll
  for (int off = 128; off > 0; off >>= 1) {
    if (tid < off) sd[tid] += sd[tid + off];
    __syncthreads();
  }
  if (tid == 0) out[2097153] = (float)exp(-sd[0]);
}

extern "C" void kernel_launch(void* const* d_in, const int* in_sizes, int n_in,
                              void* d_out, int out_size, void* d_ws, size_t ws_size,
                              hipStream_t stream) {
  const float* z_e = (const float*)d_in[0];     // [8,256,32,32]
  const float* weight = (const float*)d_in[1];  // [8192,256]
  const float* gumbel = (const float*)d_in[2];  // [8192,8192]
  float* out = (float*)d_out;  // [z_q_ste 2097152][vq_loss][perplexity][indices 8192]

  float* ws = (float*)d_ws;
  float* Arow = ws;                             // 8192 f
  int* hist = (int*)(ws + 8192);                // 8192 i
  float* lpart = ws + 16384;                    // 256 f
  int* idxbuf = (int*)(ws + 16640);             // 8192 i
  float2* cand = (float2*)(ws + 24832);         // big: 8192*64, small: 8192*8
  unsigned short* sb = (unsigned short*)(ws + 24832 + 2 * 8192 * 64);
  unsigned short* a_hi = sb;                    // 6 x 8192*256 shorts (4MB each)
  unsigned short* a_mid = sb + 2097152;
  unsigned short* a_lo = sb + 2 * 2097152;
  unsigned short* w_hi = sb + 3 * 2097152;
  unsigned short* w_mid = sb + 4 * 2097152;
  unsigned short* w_lo = sb + 5 * 2097152;
  const size_t needed = (size_t)(24832 + 2 * 8192 * 64) * 4 + 6ull * 2097152 * 2;
  const bool big = ws_size >= needed;

  float* flat2 = out;  // staged in out[0..2M); consumed before vq_gather_out

  hipMemsetAsync(hist, 0, 8192 * sizeof(int), stream);
  vq_transpose_rowsum<<<256, 256, 0, stream>>>(z_e, flat2, Arow);
  if (big) {
    vq_split<<<2048, 256, 0, stream>>>(flat2, a_hi, a_mid, a_lo);
    vq_split<<<2048, 256, 0, stream>>>(weight, w_hi, w_mid, w_lo);
    vq_score_mfma<<<dim3(64, 64), 256, 0, stream>>>(a_hi, a_mid, a_lo, w_hi, w_mid,
                                                    w_lo, gumbel, Arow, cand);
    vq_reduce_cand<<<32, 256, 0, stream>>>(cand, 64, idxbuf, hist, out + 2097154);
  } else {
    vq_score_argmax<<<dim3(64, 8), 256, 0, stream>>>(flat2, weight, gumbel, Arow, cand);
    vq_reduce_cand<<<32, 256, 0, stream>>>(cand, 8, idxbuf, hist, out + 2097154);
  }
  vq_gather_out<<<256, 256, 0, stream>>>(z_e, weight, idxbuf, out, lpart);
  vq_finalize<<<1, 256, 0, stream>>>(lpart, hist, out);
}

// Round 4
// 496.360 us; speedup vs baseline: 1.6813x; 1.2601x over previous
//
#include <hip/hip_runtime.h>
#include <math.h>

// N=B*H*W=8192 tokens, K=8192 codes, D=256 dims.
// Numerics (bit-exact vs np in rounds 2-3): first-occurrence argmax over k of
//   s = fl(g - fl(A_n - M_nk)), A_n = numpy-pairwise fp32 sum of fl(f^2),
//   M = (2f)@W^T. Round 4: 4-pass split-bf16 MFMA (hi/mid; dropped lo terms
//   give |dM| rms ~1.2e-8 -> expected flips ~1e-4), global_load_lds staging,
//   XOR-swizzled unpadded LDS (2-way banks = free), kc-loop for gumbel overlap.

typedef __attribute__((ext_vector_type(8))) short bf16x8;
typedef __attribute__((ext_vector_type(4))) float floatx4;

__device__ __forceinline__ float sq025(float q) {
  return __fmul_rn(__fmul_rn(q, q), 0.25f);
}
__device__ __forceinline__ unsigned short bf16_rne(float x) {
  unsigned int u = __float_as_uint(x);
  return (unsigned short)((u + 0x7FFFu + ((u >> 16) & 1u)) >> 16);
}
__device__ __forceinline__ float bf16f(unsigned short h) {
  return __uint_as_float(((unsigned int)h) << 16);
}
__device__ __forceinline__ void glds16(const void* g, void* l) {
  __builtin_amdgcn_global_load_lds(
      (const __attribute__((address_space(1))) unsigned int*)g,
      (__attribute__((address_space(3))) unsigned int*)l, 16, 0, 0);
}

// ---- prep A: z_e (NCHW) -> a_hi/a_mid (split of q=2z, [n][d]) + Arow ----
__global__ void vq_prep_a(const float* __restrict__ z_e,
                          unsigned short* __restrict__ a_hi,
                          unsigned short* __restrict__ a_mid,
                          float* __restrict__ Arow) {
  __shared__ float tile[256][36];
  const int bx = blockIdx.x;  // b*32 + h
  const int b = bx >> 5, h = bx & 31;
  const int tid = threadIdx.x;
  const int w = tid & 31, dg = tid >> 5;
  const size_t zbase = (size_t)b * (256 * 1024) + (size_t)h * 32;
#pragma unroll 4
  for (int it = 0; it < 32; ++it) {
    const int d = dg * 32 + it;
    tile[d][w] = 2.0f * z_e[zbase + (size_t)d * 1024 + w];  // q = 2f, exact
  }
  __syncthreads();
  const int n0 = bx * 32;
#pragma unroll 4
  for (int w2 = 0; w2 < 32; ++w2) {
    const float q = tile[tid][w2];
    const unsigned short hh = bf16_rne(q);
    const float r1 = __fsub_rn(q, bf16f(hh));
    a_hi[(size_t)(n0 + w2) * 256 + tid] = hh;
    a_mid[(size_t)(n0 + w2) * 256 + tid] = bf16_rne(r1);
  }
  // numpy-pairwise ||f||^2 from q=2f (verified bit-exact in r2/r3)
  const int tg = tid >> 3, j = tid & 7;
  float halfs[2];
#pragma unroll
  for (int hf = 0; hf < 2; ++hf) {
    float r = sq025(tile[hf * 128 + j][tg]);
#pragma unroll
    for (int i = 1; i < 16; ++i)
      r = __fadd_rn(r, sq025(tile[hf * 128 + 8 * i + j][tg]));
    const float t2 = __fadd_rn(r, __shfl_xor(r, 1, 64));
    const float t4 = __fadd_rn(t2, __shfl_xor(t2, 2, 64));
    halfs[hf] = __fadd_rn(t4, __shfl_xor(t4, 4, 64));
  }
  if (j == 0) Arow[n0 + tg] = __fadd_rn(halfs[0], halfs[1]);
}

// ---- prep W: weight -> w_hi/w_mid ----
__global__ void vq_prep_w(const float* __restrict__ weight,
                          unsigned short* __restrict__ w_hi,
                          unsigned short* __restrict__ w_mid) {
  const int u = blockIdx.x * 256 + threadIdx.x;  // float4 idx, 524288 total
  const float4 v = ((const float4*)weight)[u];
  float a[4] = {v.x, v.y, v.z, v.w};
  unsigned short rh[4], rm[4];
#pragma unroll
  for (int i = 0; i < 4; ++i) {
    rh[i] = bf16_rne(a[i]);
    rm[i] = bf16_rne(__fsub_rn(a[i], bf16f(rh[i])));
  }
  ushort4 oh = {rh[0], rh[1], rh[2], rh[3]};
  ushort4 om = {rm[0], rm[1], rm[2], rm[3]};
  ((ushort4*)w_hi)[u] = oh;
  ((ushort4*)w_mid)[u] = om;
}

// ---- MFMA score + argmax: grid (64 n-tiles, 16 k-slices), kc-loop x4 ----
__global__ __launch_bounds__(256, 2) void vq_score_mfma(
    const unsigned short* __restrict__ ah, const unsigned short* __restrict__ am,
    const unsigned short* __restrict__ wh, const unsigned short* __restrict__ wm,
    const float* __restrict__ gumbel, const float* __restrict__ Arow,
    float2* __restrict__ cand) {
  __shared__ unsigned short sA[2][128][32];  // comp, n-row, d — glds target
  __shared__ unsigned short sW[2][128][32];  // comp, k-row, d
  __shared__ float2 red[128][2];

  const int tid = threadIdx.x;
  const int wv = tid >> 6, lane = tid & 63;
  const int r16 = lane & 15, q = lane >> 4;
  const int wrow = (wv & 1) * 64, wcol = (wv >> 1) * 64;
  const int n0 = blockIdx.x * 128;
  const int sw = (r16 & 3) ^ ((r16 >> 2) & 1);  // read-side chunk swizzle
  // glds lane->global map (write side): page-local row rp, phys chunk pc
  const int rp = lane >> 2, pc = lane & 3;
  const int lc = pc ^ ((rp & 3) ^ ((rp >> 2) & 1));  // logical chunk fetched

  float Av[4][4], bv[4][4];
  int bk[4][4];
#pragma unroll
  for (int i = 0; i < 4; ++i)
#pragma unroll
    for (int rg = 0; rg < 4; ++rg) {
      Av[i][rg] = Arow[n0 + wrow + i * 16 + q * 4 + rg];
      bv[i][rg] = -3.4e38f;
      bk[i][rg] = 0x7fffffff;
    }

#pragma unroll 1
  for (int kc = 0; kc < 4; ++kc) {
    const int k0 = (blockIdx.y * 4 + kc) * 128;
    floatx4 acc[4][4];
#pragma unroll
    for (int i = 0; i < 4; ++i)
#pragma unroll
      for (int j = 0; j < 4; ++j) acc[i][j] = (floatx4){0.f, 0.f, 0.f, 0.f};

#pragma unroll 1
    for (int dc = 0; dc < 8; ++dc) {
      const int d0 = dc * 32;
      __syncthreads();
      // 32 pages of 1KB: wave wv stages pages gi=wv*8..wv*8+7
#pragma unroll
      for (int t = 0; t < 8; ++t) {
        const int gi = wv * 8 + t;
        const int m = gi >> 4, c = (gi >> 3) & 1, p = gi & 7;
        const unsigned short* gsrc = (m == 0) ? (c == 0 ? ah : am)
                                              : (c == 0 ? wh : wm);
        const int grow_ = ((m == 0) ? n0 : k0) + p * 16 + rp;
        const void* ga = gsrc + (size_t)grow_ * 256 + d0 + lc * 8;
        void* la = (m == 0) ? (void*)&sA[c][p * 16][0] : (void*)&sW[c][p * 16][0];
        glds16(ga, la);
      }
      __syncthreads();
      bf16x8 af[2][4], bf[2][4];
#pragma unroll
      for (int c = 0; c < 2; ++c)
#pragma unroll
        for (int i = 0; i < 4; ++i) {
          af[c][i] = *(const bf16x8*)&sA[c][wrow + i * 16 + r16][(q ^ sw) * 8];
          bf[c][i] = *(const bf16x8*)&sW[c][wcol + i * 16 + r16][(q ^ sw) * 8];
        }
#pragma unroll
      for (int i = 0; i < 4; ++i)
#pragma unroll
        for (int j = 0; j < 4; ++j) {
          floatx4 a = acc[i][j];
          a = __builtin_amdgcn_mfma_f32_16x16x32_bf16(af[1][i], bf[1][j], a, 0, 0, 0);
          a = __builtin_amdgcn_mfma_f32_16x16x32_bf16(af[1][i], bf[0][j], a, 0, 0, 0);
          a = __builtin_amdgcn_mfma_f32_16x16x32_bf16(af[0][i], bf[1][j], a, 0, 0, 0);
          a = __builtin_amdgcn_mfma_f32_16x16x32_bf16(af[0][i], bf[0][j], a, 0, 0, 0);
          acc[i][j] = a;
        }
    }
    // per-kc epilogue: s = fl(g - fl(A - M)); running first-occurrence argmax
#pragma unroll
    for (int i = 0; i < 4; ++i)
#pragma unroll
      for (int rg = 0; rg < 4; ++rg) {
        const int nloc = wrow + i * 16 + q * 4 + rg;
        const float* grow = gumbel + (size_t)(n0 + nloc) * 8192 + k0 + wcol + r16;
#pragma unroll
        for (int j = 0; j < 4; ++j) {  // ascending k
          const float t2 = __fsub_rn(Av[i][rg], acc[i][j][rg]);
          const float s = __fsub_rn(grow[j * 16], t2);
          const int kk = k0 + wcol + j * 16 + r16;
          if (s > bv[i][rg]) { bv[i][rg] = s; bk[i][rg] = kk; }
        }
      }
  }
  // reduce across the 16 lanes sharing a token row (r16 = col dimension)
#pragma unroll
  for (int i = 0; i < 4; ++i)
#pragma unroll
    for (int rg = 0; rg < 4; ++rg) {
      float v = bv[i][rg];
      int kkk = bk[i][rg];
#pragma unroll
      for (int m = 1; m < 16; m <<= 1) {
        const float ov = __shfl_xor(v, m, 64);
        const int ok = __shfl_xor(kkk, m, 64);
        if (ov > v || (ov == v && ok < kkk)) { v = ov; kkk = ok; }
      }
      if (r16 == 0) red[wrow + i * 16 + q * 4 + rg][wv >> 1] = make_float2(v, (float)kkk);
    }
  __syncthreads();
  if (tid < 128) {
    float2 bb = red[tid][0];  // lower-k half first: first-occurrence ties
    const float2 c = red[tid][1];
    if (c.x > bb.x || (c.x == bb.x && c.y < bb.y)) bb = c;
    cand[(size_t)blockIdx.y * 8192 + n0 + tid] = bb;  // slice-major
  }
}

// ---- reduce 16 slice-candidates per token (coalesced slice-major reads) ----
__global__ void vq_reduce_cand(const float2* __restrict__ cand, int* __restrict__ idxbuf,
                               int* __restrict__ hist, float* __restrict__ out_idx) {
  const int n = blockIdx.x * 256 + threadIdx.x;
  float2 b = cand[n];
#pragma unroll
  for (int s = 1; s < 16; ++s) {  // ascending-k slices
    const float2 c = cand[(size_t)s * 8192 + n];
    if (c.x > b.x || (c.x == b.x && c.y < b.y)) b = c;
  }
  const int k = (int)b.y;
  idxbuf[n] = k;
  out_idx[n] = b.y;
  atomicAdd(&hist[k], 1);
}

// ---- gather z_q, STE output (NCHW), loss partials (512 blocks) ----
__global__ void vq_gather_out(const float* __restrict__ z_e, const float* __restrict__ weight,
                              const int* __restrict__ idxbuf, float* __restrict__ out0,
                              float* __restrict__ lpart) {
  __shared__ int sidx[32];
  __shared__ float sred[256];
  const int bx2 = blockIdx.x;
  const int bx = bx2 >> 1, half = bx2 & 1;
  const int b = bx >> 5, h = bx & 31;
  const int tid = threadIdx.x;
  if (tid < 32) sidx[tid] = idxbuf[bx * 32 + tid];
  __syncthreads();
  const int w = tid & 31, dg = tid >> 5;
  const int srow = sidx[w];
  const size_t base = (size_t)b * (256 * 1024) + (size_t)h * 32 + w;
  float part = 0.f;
#pragma unroll 4
  for (int it = 0; it < 16; ++it) {
    const int d = half * 128 + dg * 16 + it;
    const float qv = weight[(size_t)srow * 256 + d];
    const size_t a = base + (size_t)d * 1024;
    const float ze = z_e[a];
    const float df = qv - ze;
    out0[a] = ze + df;  // fl(ze + fl(q - ze)) per reference STE
    part = fmaf(df, df, part);
  }
  sred[tid] = part;
  __syncthreads();
#pragma unroll
  for (int off = 128; off > 0; off >>= 1) {
    if (tid < off) sred[tid] += sred[tid + off];
    __syncthreads();
  }
  if (tid == 0) lpart[bx2] = sred[0];
}

// ---- scalars: vq_loss, perplexity ----
__global__ void vq_finalize(const float* __restrict__ lpart, const int* __restrict__ hist,
                            float* __restrict__ out) {
  __shared__ double sd[256];
  const int tid = threadIdx.x;
  sd[tid] = (double)lpart[tid] + (double)lpart[tid + 256];
  __syncthreads();
#pragma unroll
  for (int off = 128; off > 0; off >>= 1) {
    if (tid < off) sd[tid] += sd[tid + off];
    __syncthreads();
  }
  if (tid == 0) out[2097152] = (float)(1.25 * sd[0] / 2097152.0);
  __syncthreads();
  double hh = 0.0;
#pragma unroll 4
  for (int qq = 0; qq < 32; ++qq) {
    const int c = hist[tid * 32 + qq];
    const double p = (double)c / 8192.0;
    hh += p * log(p + 1e-10);
  }
  sd[tid] = hh;
  __syncthreads();
#pragma unroll
  for (int off = 128; off > 0; off >>= 1) {
    if (tid < off) sd[tid] += sd[tid + off];
    __syncthreads();
  }
  if (tid == 0) out[2097153] = (float)exp(-sd[0]);
}

extern "C" void kernel_launch(void* const* d_in, const int* in_sizes, int n_in,
                              void* d_out, int out_size, void* d_ws, size_t ws_size,
                              hipStream_t stream) {
  const float* z_e = (const float*)d_in[0];     // [8,256,32,32]
  const float* weight = (const float*)d_in[1];  // [8192,256]
  const float* gumbel = (const float*)d_in[2];  // [8192,8192]
  float* out = (float*)d_out;  // [z_q_ste 2097152][vq_loss][perplexity][indices 8192]

  float* ws = (float*)d_ws;
  float* Arow = ws;                         // 8192 f
  int* hist = (int*)(ws + 8192);            // 8192 i
  float* lpart = ws + 16384;                // 512 f
  int* idxbuf = (int*)(ws + 16896);         // 8192 i
  float2* cand = (float2*)(ws + 25088);     // 16*8192 float2 = 262144 f
  unsigned short* sb = (unsigned short*)(ws + 25088 + 262144);
  unsigned short* a_hi = sb;                // 4 x 8192*256 shorts (4MB each)
  unsigned short* a_mid = sb + 2097152;
  unsigned short* w_hi = sb + 2 * 2097152;
  unsigned short* w_mid = sb + 3 * 2097152;

  hipMemsetAsync(hist, 0, 8192 * sizeof(int), stream);
  vq_prep_a<<<256, 256, 0, stream>>>(z_e, a_hi, a_mid, Arow);
  vq_prep_w<<<2048, 256, 0, stream>>>(weight, w_hi, w_mid);
  vq_score_mfma<<<dim3(64, 16), 256, 0, stream>>>(a_hi, a_mid, w_hi, w_mid,
                                                  gumbel, Arow, cand);
  vq_reduce_cand<<<32, 256, 0, stream>>>(cand, idxbuf, hist, out + 2097154);
  vq_gather_out<<<512, 256, 0, stream>>>(z_e, weight, idxbuf, out, lpart);
  vq_finalize<<<1, 256, 0, stream>>>(lpart, hist, out);
}